// Round 9
// baseline (1119.191 us; speedup 1.0000x reference)
//
#include <hip/hip_runtime.h>

typedef __bf16 bf16;
typedef __attribute__((ext_vector_type(8))) __bf16 bf16x8;
typedef __attribute__((ext_vector_type(2))) __bf16 bf16x2;
typedef __attribute__((ext_vector_type(4))) float f32x4;
typedef __attribute__((ext_vector_type(16))) float f32x16;
typedef __attribute__((ext_vector_type(8))) unsigned short ushort8;   // 16B
typedef __attribute__((ext_vector_type(4))) unsigned short ushort4v;  // 8B

__device__ __forceinline__ unsigned short f2bf(float f) {
    union { float f; unsigned int u; } v; v.f = f;
    unsigned int u = v.u;
    return (unsigned short)((u + 0x7fffu + ((u >> 16) & 1u)) >> 16);
}

#if __has_builtin(__builtin_amdgcn_cvt_pk_bf16_f32)
__device__ __forceinline__ unsigned int pk2bf(float a, float b) {
    union { bf16x2 v; unsigned int u; } c;
    c.v = __builtin_amdgcn_cvt_pk_bf16_f32(a, b);
    return c.u;
}
#else
__device__ __forceinline__ unsigned int pk2bf(float a, float b) {
    return (unsigned int)f2bf(a) | ((unsigned int)f2bf(b) << 16);
}
#endif

__device__ __forceinline__ f32x4 mfma16(bf16x8 a, bf16x8 b, f32x4 c) {
    return __builtin_amdgcn_mfma_f32_16x16x32_bf16(a, b, c, 0, 0, 0);
}
__device__ __forceinline__ f32x16 mfma32(bf16x8 a, bf16x8 b, f32x16 c) {
    return __builtin_amdgcn_mfma_f32_32x32x16_bf16(a, b, c, 0, 0, 0);
}

// ---------------- fused fp32 -> bf16 convert ----------------
__global__ void cvt3_f32_bf16(const float* __restrict__ x, const float* __restrict__ wq,
                              const float* __restrict__ wp,
                              unsigned short* __restrict__ xb, unsigned short* __restrict__ wqb,
                              unsigned short* __restrict__ wpb) {
    int i = blockIdx.x * 256 + threadIdx.x;   // float4 index
    const float* in; unsigned short* out; int base;
    if (i < 1572864)      { in = x;  out = xb;  base = i; }
    else if (i < 2015232) { in = wq; out = wqb; base = i - 1572864; }
    else if (i < 2162688) { in = wp; out = wpb; base = i - 2015232; }
    else return;
    float4 f = reinterpret_cast<const float4*>(in)[base];
    union { ushort4v v; unsigned int u[2]; } o;
    o.u[0] = pk2bf(f.x, f.y);
    o.u[1] = pk2bf(f.z, f.w);
    reinterpret_cast<ushort4v*>(out)[base] = o.v;
}

// key permutation for 32x32 S^T C-layout -> PV A-layout:  p: a -> bits (a0,a1,a3,a4,a2)
__device__ __forceinline__ int kperm(int k5) {
    return (k5 & 3) | (((k5 >> 3) & 1) << 2) | (((k5 >> 4) & 1) << 3) | (((k5 >> 2) & 1) << 4);
}
__device__ __forceinline__ int kperm_inv(int p5) {
    return (p5 & 3) | (((p5 >> 4) & 1) << 2) | (((p5 >> 2) & 1) << 3) | (((p5 >> 3) & 1) << 4);
}

// ---------------- QKV GEMM -> fragment-ready chunked layouts ----------------
// Layout identical to R8 (verified): 1KB chunks, lane l reads ushort index l*8.
// Qf chunk (bh, qg, kq):      lane h2*32+l31 holds Q[qg*32+l31][kq*16+h2*8 .. +7] (scaled)
// Kf chunk (bh, kg, kq):      lane h2*32+p   holds K[kg*32+n5][kq*16+h2*8 .. +7], p=kperm(n5)
// Vf chunk (bh, kg, dn*2+f):  lane hv*32+dl  holds V[key=kg*32+f*16+hv*8+j][d=dn*32+dl]
// NEW: epilogue goes C-regs -> LDS (bf16) -> coalesced b128 global stores.
__global__ __launch_bounds__(256) void qkv_gemm(const unsigned short* __restrict__ A,
                                                const unsigned short* __restrict__ W,
                                                unsigned short* __restrict__ Qf,
                                                unsigned short* __restrict__ Kf,
                                                unsigned short* __restrict__ Vf) {
    __shared__ __align__(16) char smem[40960];
    unsigned short* As = (unsigned short*)smem;            // 128x40
    unsigned short* Bs = (unsigned short*)(smem + 20480);  // 128x40
    unsigned short* T  = (unsigned short*)smem;            // epilogue tile 128x136
    const int t = threadIdx.x;
    const int w = t >> 6, l = t & 63;
    const int wm = (w >> 1) * 64, wn = (w & 1) * 64;
    const int lr = l & 15, lq = l >> 4;
    const int m0 = blockIdx.y * 128, n0 = blockIdx.x * 128;
    f32x4 acc[4][4] = {};
    for (int k0 = 0; k0 < 768; k0 += 32) {
        __syncthreads();
#pragma unroll
        for (int i = 0; i < 2; ++i) {
            int v = t + i * 256;
            int r = v >> 2, c8 = (v & 3) * 8;
            *reinterpret_cast<ushort8*>(&As[r * 40 + c8]) =
                *reinterpret_cast<const ushort8*>(&A[(m0 + r) * 768 + k0 + c8]);
            *reinterpret_cast<ushort8*>(&Bs[r * 40 + c8]) =
                *reinterpret_cast<const ushort8*>(&W[(n0 + r) * 768 + k0 + c8]);
        }
        __syncthreads();
        bf16x8 af[4], bfr[4];
#pragma unroll
        for (int mt = 0; mt < 4; ++mt)
            af[mt] = *reinterpret_cast<const bf16x8*>(&As[(wm + mt * 16 + lr) * 40 + lq * 8]);
#pragma unroll
        for (int nt = 0; nt < 4; ++nt)
            bfr[nt] = *reinterpret_cast<const bf16x8*>(&Bs[(wn + nt * 16 + lr) * 40 + lq * 8]);
#pragma unroll
        for (int mt = 0; mt < 4; ++mt)
#pragma unroll
            for (int nt = 0; nt < 4; ++nt)
                acc[mt][nt] = mfma16(af[mt], bfr[nt], acc[mt][nt]);
    }
    // ---- epilogue: C tile -> LDS (V region transposed) -> coalesced b128 stores ----
    const int tsel = n0 / 768;   // whole block is one of Q/K/V
    __syncthreads();             // As/Bs fragment reads done; reuse as T
    if (tsel < 2) {
#pragma unroll
        for (int nt = 0; nt < 4; ++nt)
#pragma unroll
            for (int mt = 0; mt < 4; ++mt)
#pragma unroll
                for (int r = 0; r < 4; ++r) {
                    int row = wm + mt * 16 + lq * 4 + r;
                    int col = wn + nt * 16 + lr;
                    float val = acc[mt][nt][r];
                    if (tsel == 0) val *= 0.14724444f;   // SCALE*log2e
                    T[row * 136 + col] = f2bf(val);
                }
    } else {
#pragma unroll
        for (int nt = 0; nt < 4; ++nt)
#pragma unroll
            for (int mt = 0; mt < 4; ++mt)
#pragma unroll
                for (int r = 0; r < 4; ++r) {
                    int row = wm + mt * 16 + lq * 4 + r;   // key token
                    int col = wn + nt * 16 + lr;           // feature
                    T[col * 136 + row] = f2bf(acc[mt][nt][r]);  // transposed
                }
    }
    __syncthreads();
    if (tsel < 2) {
        // 2048 (row-group x c8) b128 stores; 8 per thread, coalesced in store order
#pragma unroll
        for (int i = 0; i < 8; ++i) {
            int idx = t + i * 256;
            int pos31 = idx & 31;          // store position within 32-group
            int rest = idx >> 5;           // 64 = c8(16) x qg(4)
            int c8 = rest & 15, qg = rest >> 4;
            int l31 = (tsel == 1) ? kperm_inv(pos31) : pos31;  // token row in tile
            int gncol = n0 + c8 * 8;
            int rem = gncol - tsel * 768;
            int head = rem / 96, d = rem - head * 96;
            int kq = d >> 4, h2 = (d >> 3) & 1;
            int gm = m0 + qg * 32 + l31;
            int b = gm >> 12, nn = gm & 4095;
            int bh = b * 8 + head;
            long chunk = (long)(bh * 128 + (nn >> 5)) * 6 + kq;
            ushort8 v8 = *reinterpret_cast<const ushort8*>(&T[(qg * 32 + l31) * 136 + c8 * 8]);
            unsigned short* dst = (tsel == 0) ? Qf : Kf;
            *reinterpret_cast<ushort8*>(&dst[(chunk << 9) + ((h2 * 32 + pos31) << 3)]) = v8;
        }
    } else {
#pragma unroll
        for (int i = 0; i < 8; ++i) {
            int idx = t + i * 256;
            int dl = idx & 31;
            int rr = idx >> 5;             // 64 = r8(16) x cmb(4)
            int r8 = rr & 15, cmb = rr >> 4;
            int col = cmb * 32 + dl;       // feature col within 128-tile
            int gncol = n0 + col;
            int rem = gncol - 1536;
            int head = rem / 96, d = rem - head * 96;
            int dn = d >> 5;               // d&31 == dl
            int keybase = m0 + r8 * 8;     // 8 consecutive keys
            int b = keybase >> 12, nn = keybase & 4095;
            int kg = nn >> 5, f = (nn >> 4) & 1, hv = (nn >> 3) & 1;
            int bh = b * 8 + head;
            long chunk = (long)(bh * 128 + kg) * 6 + dn * 2 + f;
            ushort8 v8 = *reinterpret_cast<const ushort8*>(&T[col * 136 + r8 * 8]);
            *reinterpret_cast<ushort8*>(&Vf[(chunk << 9) + ((hv * 32 + dl) << 3)]) = v8;
        }
    }
}

// ---------------- Flash attention: barrier-free loop, 4-way kv split, grid 1024 ----------------
// 256 thr = 4 waves, wk = w in 0..3: keys [wk*1024, +1024), 32 iters of 32. All waves share
// the block's 64 q-rows (qn=2 x 32). Coalesced global b128 operand loads from frag chunks.
// XCD swizzle: bh = (b0&7)*2 + (kk>>6) pins each bh's K+V (1.57MB) to one XCD L2.
__global__ __launch_bounds__(256, 4) void attn_kernel(const unsigned short* __restrict__ Qf,
                                                      const unsigned short* __restrict__ Kf,
                                                      const unsigned short* __restrict__ Vf,
                                                      unsigned short* __restrict__ Og) {
    __shared__ __align__(16) float red[64 * 132];   // 4-way epilogue reduce (pad 132)
    const int t = threadIdx.x;
    const int w = t >> 6, l = t & 63;
    const int wk = w;
    const int l31 = l & 31, h = l >> 5;
    const int b0 = blockIdx.x;
    const int kk = b0 >> 3;
    const int bh = (b0 & 7) * 2 + (kk >> 6);
    const int qt = kk & 63;
    const int q0 = qt * 64;
    const int voff = l << 3;   // lane's ushort offset within a chunk

    // Q fragments: 12 coalesced b128 loads, loop-invariant
    bf16x8 aq[2][6];
#pragma unroll
    for (int qn = 0; qn < 2; ++qn) {
        long qb = ((long)((bh * 128 + qt * 2 + qn) * 6)) << 9;
#pragma unroll
        for (int kq = 0; kq < 6; ++kq)
            aq[qn][kq] = *reinterpret_cast<const bf16x8*>(&Qf[qb + (kq << 9) + voff]);
    }

    bf16x8 ones8;
#pragma unroll
    for (int i = 0; i < 8; ++i) ones8[i] = (__bf16)1.0f;

    f32x16 acc[2][3] = {};   // [qn][dn]
    f32x16 acc_l[2] = {};

    for (int it = 0; it < 32; ++it) {
        const int kt = wk * 32 + it;
        const long kbase = ((long)((bh * 128 + kt) * 6)) << 9;
        // S^T = K_perm Q^T (32x32x16)
        f32x16 s[2] = {};
#pragma unroll
        for (int kq = 0; kq < 6; ++kq) {
            bf16x8 bk = *reinterpret_cast<const bf16x8*>(&Kf[kbase + (kq << 9) + voff]);
            s[0] = mfma32(bk, aq[0][kq], s[0]);
            s[1] = mfma32(bk, aq[1][kq], s[1]);
        }
        // p = exp2(s); C-reg -> PV A-frag slot map: frag f slot j <- reg (j&3)+8*((j>>2)&1)+4*f
        union PF { unsigned int u[4]; bf16x8 v8; } p[2][2];
#pragma unroll
        for (int qn = 0; qn < 2; ++qn) {
            float e[16];
#pragma unroll
            for (int r = 0; r < 16; ++r) e[r] = __builtin_amdgcn_exp2f(s[qn][r]);
#pragma unroll
            for (int f = 0; f < 2; ++f) {
                p[qn][f].u[0] = pk2bf(e[4 * f + 0], e[4 * f + 1]);
                p[qn][f].u[1] = pk2bf(e[4 * f + 2], e[4 * f + 3]);
                p[qn][f].u[2] = pk2bf(e[8 + 4 * f + 0], e[8 + 4 * f + 1]);
                p[qn][f].u[3] = pk2bf(e[8 + 4 * f + 2], e[8 + 4 * f + 3]);
            }
        }
        // O += P V (32x32x16), V fragments straight from L2
#pragma unroll
        for (int dn = 0; dn < 3; ++dn) {
#pragma unroll
            for (int f = 0; f < 2; ++f) {
                bf16x8 vb = *reinterpret_cast<const bf16x8*>(
                    &Vf[kbase + ((dn * 2 + f) << 9) + voff]);
                acc[0][dn] = mfma32(p[0][f].v8, vb, acc[0][dn]);
                acc[1][dn] = mfma32(p[1][f].v8, vb, acc[1][dn]);
            }
        }
#pragma unroll
        for (int qn = 0; qn < 2; ++qn)
#pragma unroll
            for (int f = 0; f < 2; ++f)
                acc_l[qn] = mfma32(p[qn][f].v8, ones8, acc_l[qn]);
    }

    // ---- 4-way cross-wave reduce: waves 1..3 dump 8 f32x16 slots, wave 0 accumulates ----
#pragma unroll
    for (int pwave = 1; pwave < 4; ++pwave) {
        __syncthreads();
        if (w == pwave) {
#pragma unroll
            for (int qn = 0; qn < 2; ++qn) {
#pragma unroll
                for (int dn = 0; dn < 3; ++dn) {
                    int slot = qn * 3 + dn;
#pragma unroll
                    for (int u = 0; u < 4; ++u) {
                        f32x4 tmp;
#pragma unroll
                        for (int j = 0; j < 4; ++j) tmp[j] = acc[qn][dn][u * 4 + j];
                        *reinterpret_cast<f32x4*>(&red[l * 132 + slot * 16 + u * 4]) = tmp;
                    }
                }
#pragma unroll
                for (int u = 0; u < 4; ++u) {
                    f32x4 tmp;
#pragma unroll
                    for (int j = 0; j < 4; ++j) tmp[j] = acc_l[qn][u * 4 + j];
                    *reinterpret_cast<f32x4*>(&red[l * 132 + (6 + qn) * 16 + u * 4]) = tmp;
                }
            }
        }
        __syncthreads();
        if (w == 0) {
#pragma unroll
            for (int qn = 0; qn < 2; ++qn) {
#pragma unroll
                for (int dn = 0; dn < 3; ++dn) {
                    int slot = qn * 3 + dn;
#pragma unroll
                    for (int u = 0; u < 4; ++u) {
                        f32x4 tmp = *reinterpret_cast<const f32x4*>(&red[l * 132 + slot * 16 + u * 4]);
#pragma unroll
                        for (int j = 0; j < 4; ++j) acc[qn][dn][u * 4 + j] += tmp[j];
                    }
                }
#pragma unroll
                for (int u = 0; u < 4; ++u) {
                    f32x4 tmp = *reinterpret_cast<const f32x4*>(&red[l * 132 + (6 + qn) * 16 + u * 4]);
#pragma unroll
                    for (int j = 0; j < 4; ++j) acc_l[qn][u * 4 + j] += tmp[j];
                }
            }
        }
    }
    if (w == 0) {
        // normalize + write attn_out[b][n][head*96+d] (bf16 scratch)
        const int b = bh >> 3, head = bh & 7;
#pragma unroll
        for (int qn = 0; qn < 2; ++qn) {
#pragma unroll
            for (int reg = 0; reg < 16; ++reg) {
                int qloc = (reg & 3) + 8 * (reg >> 2) + 4 * h;
                int n = q0 + qn * 32 + qloc;
                float inv = 1.f / acc_l[qn][reg];
                int rowoff = (b * 4096 + n) * 768 + head * 96;
#pragma unroll
                for (int dn = 0; dn < 3; ++dn)
                    Og[rowoff + dn * 32 + l31] = f2bf(acc[qn][dn][reg] * inv);
            }
        }
    }
}

// ---------------- proj GEMM: [8192x768] x [768x768]^T -> FP32 out ----------------
__global__ __launch_bounds__(256) void proj_gemm(const unsigned short* __restrict__ A,
                                                 const unsigned short* __restrict__ W,
                                                 float* __restrict__ out) {
    __shared__ __align__(16) unsigned short As[128 * 40];
    __shared__ __align__(16) unsigned short Bs[128 * 40];
    const int t = threadIdx.x;
    const int w = t >> 6, l = t & 63;
    const int wm = (w >> 1) * 64, wn = (w & 1) * 64;
    const int lr = l & 15, lq = l >> 4;
    const int m0 = blockIdx.y * 128, n0 = blockIdx.x * 128;
    f32x4 acc[4][4] = {};
    for (int k0 = 0; k0 < 768; k0 += 32) {
        __syncthreads();
#pragma unroll
        for (int i = 0; i < 2; ++i) {
            int v = t + i * 256;
            int r = v >> 2, c8 = (v & 3) * 8;
            *reinterpret_cast<ushort8*>(&As[r * 40 + c8]) =
                *reinterpret_cast<const ushort8*>(&A[(m0 + r) * 768 + k0 + c8]);
            *reinterpret_cast<ushort8*>(&Bs[r * 40 + c8]) =
                *reinterpret_cast<const ushort8*>(&W[(n0 + r) * 768 + k0 + c8]);
        }
        __syncthreads();
        bf16x8 af[4], bfr[4];
#pragma unroll
        for (int mt = 0; mt < 4; ++mt)
            af[mt] = *reinterpret_cast<const bf16x8*>(&As[(wm + mt * 16 + lr) * 40 + lq * 8]);
#pragma unroll
        for (int nt = 0; nt < 4; ++nt)
            bfr[nt] = *reinterpret_cast<const bf16x8*>(&Bs[(wn + nt * 16 + lr) * 40 + lq * 8]);
#pragma unroll
        for (int mt = 0; mt < 4; ++mt)
#pragma unroll
            for (int nt = 0; nt < 4; ++nt)
                acc[mt][nt] = mfma16(af[mt], bfr[nt], acc[mt][nt]);
    }
#pragma unroll
    for (int nt = 0; nt < 4; ++nt) {
        int gn = n0 + wn + nt * 16 + lr;
#pragma unroll
        for (int mt = 0; mt < 4; ++mt) {
#pragma unroll
            for (int r = 0; r < 4; ++r) {
                int gm = m0 + wm + mt * 16 + lq * 4 + r;
                out[gm * 768 + gn] = acc[mt][nt][r];
            }
        }
    }
}

extern "C" void kernel_launch(void* const* d_in, const int* in_sizes, int n_in,
                              void* d_out, int out_size, void* d_ws, size_t ws_size,
                              hipStream_t stream) {
    const float* x     = (const float*)d_in[0];   // [2,4096,768] fp32
    const float* wqkv  = (const float*)d_in[1];   // [2304,768] fp32
    const float* wproj = (const float*)d_in[2];   // [768,768] fp32
    float* out = (float*)d_out;                   // fp32 [2,4096,768]
    char* ws = (char*)d_ws;
    unsigned short* xb     = (unsigned short*)(ws);             // 12582912
    unsigned short* wqkvb  = (unsigned short*)(ws + 12582912);  // 3538944
    unsigned short* wprojb = (unsigned short*)(ws + 16121856);  // 1179648
    unsigned short* Qf     = (unsigned short*)(ws + 17301504);  // frag chunks
    unsigned short* Kf     = (unsigned short*)(ws + 29884416);  // frag chunks
    unsigned short* Vf     = (unsigned short*)(ws + 42467328);  // frag chunks
    unsigned short* attnb  = xb;                                // reuse: [B,N,C] bf16

    cvt3_f32_bf16<<<8448, 256, 0, stream>>>(x, wqkv, wproj, xb, wqkvb, wprojb);
    qkv_gemm<<<dim3(18, 64), 256, 0, stream>>>(xb, wqkvb, Qf, Kf, Vf);
    attn_kernel<<<1024, 256, 0, stream>>>(Qf, Kf, Vf, attnb);
    proj_gemm<<<dim3(6, 64), 256, 0, stream>>>(attnb, wprojb, out);
}

// Round 10
// 283.914 us; speedup vs baseline: 3.9420x; 3.9420x over previous
//
#include <hip/hip_runtime.h>

typedef __bf16 bf16;
typedef __attribute__((ext_vector_type(8))) __bf16 bf16x8;
typedef __attribute__((ext_vector_type(2))) __bf16 bf16x2;
typedef __attribute__((ext_vector_type(4))) float f32x4;
typedef __attribute__((ext_vector_type(16))) float f32x16;
typedef __attribute__((ext_vector_type(8))) unsigned short ushort8;   // 16B
typedef __attribute__((ext_vector_type(4))) unsigned short ushort4v;  // 8B

__device__ __forceinline__ unsigned short f2bf(float f) {
    union { float f; unsigned int u; } v; v.f = f;
    unsigned int u = v.u;
    return (unsigned short)((u + 0x7fffu + ((u >> 16) & 1u)) >> 16);
}

#if __has_builtin(__builtin_amdgcn_cvt_pk_bf16_f32)
__device__ __forceinline__ unsigned int pk2bf(float a, float b) {
    union { bf16x2 v; unsigned int u; } c;
    c.v = __builtin_amdgcn_cvt_pk_bf16_f32(a, b);
    return c.u;
}
#else
__device__ __forceinline__ unsigned int pk2bf(float a, float b) {
    return (unsigned int)f2bf(a) | ((unsigned int)f2bf(b) << 16);
}
#endif

__device__ __forceinline__ f32x4 mfma16(bf16x8 a, bf16x8 b, f32x4 c) {
    return __builtin_amdgcn_mfma_f32_16x16x32_bf16(a, b, c, 0, 0, 0);
}
__device__ __forceinline__ f32x16 mfma32(bf16x8 a, bf16x8 b, f32x16 c) {
    return __builtin_amdgcn_mfma_f32_32x32x16_bf16(a, b, c, 0, 0, 0);
}

// ---------------- fused fp32 -> bf16 convert ----------------
__global__ void cvt3_f32_bf16(const float* __restrict__ x, const float* __restrict__ wq,
                              const float* __restrict__ wp,
                              unsigned short* __restrict__ xb, unsigned short* __restrict__ wqb,
                              unsigned short* __restrict__ wpb) {
    int i = blockIdx.x * 256 + threadIdx.x;   // float4 index
    const float* in; unsigned short* out; int base;
    if (i < 1572864)      { in = x;  out = xb;  base = i; }
    else if (i < 2015232) { in = wq; out = wqb; base = i - 1572864; }
    else if (i < 2162688) { in = wp; out = wpb; base = i - 2015232; }
    else return;
    float4 f = reinterpret_cast<const float4*>(in)[base];
    union { ushort4v v; unsigned int u[2]; } o;
    o.u[0] = pk2bf(f.x, f.y);
    o.u[1] = pk2bf(f.z, f.w);
    reinterpret_cast<ushort4v*>(out)[base] = o.v;
}

// key permutation for 32x32 S^T C-layout -> PV A-layout:  p: a -> bits (a0,a1,a3,a4,a2)
__device__ __forceinline__ int kperm(int k5) {
    return (k5 & 3) | (((k5 >> 3) & 1) << 2) | (((k5 >> 4) & 1) << 3) | (((k5 >> 2) & 1) << 4);
}
__device__ __forceinline__ int kperm_inv(int p5) {
    return (p5 & 3) | (((p5 >> 4) & 1) << 2) | (((p5 >> 2) & 1) << 3) | (((p5 >> 3) & 1) << 4);
}

// ---------------- QKV GEMM -> fragment-ready chunked layouts (R9 version, kept) ----------------
// Qf chunk (bh, qg, kq):      lane h2*32+l31 holds Q[qg*32+l31][kq*16+h2*8 .. +7] (scaled)
// Kf chunk (bh, kg, kq):      lane h2*32+p   holds K[kg*32+n5][kq*16+h2*8 .. +7], p=kperm(n5)
// Vf chunk (bh, kg, dn*2+f):  lane hv*32+dl  holds V[key=kg*32+f*16+hv*8+j][d=dn*32+dl]
// Epilogue: C-regs -> LDS (bf16, V transposed) -> coalesced b128 global stores.
__global__ __launch_bounds__(256) void qkv_gemm(const unsigned short* __restrict__ A,
                                                const unsigned short* __restrict__ W,
                                                unsigned short* __restrict__ Qf,
                                                unsigned short* __restrict__ Kf,
                                                unsigned short* __restrict__ Vf) {
    __shared__ __align__(16) char smem[40960];
    unsigned short* As = (unsigned short*)smem;            // 128x40
    unsigned short* Bs = (unsigned short*)(smem + 20480);  // 128x40
    unsigned short* T  = (unsigned short*)smem;            // epilogue tile 128x136
    const int t = threadIdx.x;
    const int w = t >> 6, l = t & 63;
    const int wm = (w >> 1) * 64, wn = (w & 1) * 64;
    const int lr = l & 15, lq = l >> 4;
    const int m0 = blockIdx.y * 128, n0 = blockIdx.x * 128;
    f32x4 acc[4][4] = {};
    for (int k0 = 0; k0 < 768; k0 += 32) {
        __syncthreads();
#pragma unroll
        for (int i = 0; i < 2; ++i) {
            int v = t + i * 256;
            int r = v >> 2, c8 = (v & 3) * 8;
            *reinterpret_cast<ushort8*>(&As[r * 40 + c8]) =
                *reinterpret_cast<const ushort8*>(&A[(m0 + r) * 768 + k0 + c8]);
            *reinterpret_cast<ushort8*>(&Bs[r * 40 + c8]) =
                *reinterpret_cast<const ushort8*>(&W[(n0 + r) * 768 + k0 + c8]);
        }
        __syncthreads();
        bf16x8 af[4], bfr[4];
#pragma unroll
        for (int mt = 0; mt < 4; ++mt)
            af[mt] = *reinterpret_cast<const bf16x8*>(&As[(wm + mt * 16 + lr) * 40 + lq * 8]);
#pragma unroll
        for (int nt = 0; nt < 4; ++nt)
            bfr[nt] = *reinterpret_cast<const bf16x8*>(&Bs[(wn + nt * 16 + lr) * 40 + lq * 8]);
#pragma unroll
        for (int mt = 0; mt < 4; ++mt)
#pragma unroll
            for (int nt = 0; nt < 4; ++nt)
                acc[mt][nt] = mfma16(af[mt], bfr[nt], acc[mt][nt]);
    }
    // ---- epilogue: C tile -> LDS (V region transposed) -> coalesced b128 stores ----
    const int tsel = n0 / 768;   // whole block is one of Q/K/V
    __syncthreads();             // As/Bs fragment reads done; reuse as T
    if (tsel < 2) {
#pragma unroll
        for (int nt = 0; nt < 4; ++nt)
#pragma unroll
            for (int mt = 0; mt < 4; ++mt)
#pragma unroll
                for (int r = 0; r < 4; ++r) {
                    int row = wm + mt * 16 + lq * 4 + r;
                    int col = wn + nt * 16 + lr;
                    float val = acc[mt][nt][r];
                    if (tsel == 0) val *= 0.14724444f;   // SCALE*log2e
                    T[row * 136 + col] = f2bf(val);
                }
    } else {
#pragma unroll
        for (int nt = 0; nt < 4; ++nt)
#pragma unroll
            for (int mt = 0; mt < 4; ++mt)
#pragma unroll
                for (int r = 0; r < 4; ++r) {
                    int row = wm + mt * 16 + lq * 4 + r;   // key token
                    int col = wn + nt * 16 + lr;           // feature
                    T[col * 136 + row] = f2bf(acc[mt][nt][r]);  // transposed
                }
    }
    __syncthreads();
    if (tsel < 2) {
#pragma unroll
        for (int i = 0; i < 8; ++i) {
            int idx = t + i * 256;
            int pos31 = idx & 31;          // store position within 32-group
            int rest = idx >> 5;           // 64 = c8(16) x qg(4)
            int c8 = rest & 15, qg = rest >> 4;
            int l31 = (tsel == 1) ? kperm_inv(pos31) : pos31;  // token row in tile
            int gncol = n0 + c8 * 8;
            int rem = gncol - tsel * 768;
            int head = rem / 96, d = rem - head * 96;
            int kq = d >> 4, h2 = (d >> 3) & 1;
            int gm = m0 + qg * 32 + l31;
            int b = gm >> 12, nn = gm & 4095;
            int bh = b * 8 + head;
            long chunk = (long)(bh * 128 + (nn >> 5)) * 6 + kq;
            ushort8 v8 = *reinterpret_cast<const ushort8*>(&T[(qg * 32 + l31) * 136 + c8 * 8]);
            unsigned short* dst = (tsel == 0) ? Qf : Kf;
            *reinterpret_cast<ushort8*>(&dst[(chunk << 9) + ((h2 * 32 + pos31) << 3)]) = v8;
        }
    } else {
#pragma unroll
        for (int i = 0; i < 8; ++i) {
            int idx = t + i * 256;
            int dl = idx & 31;
            int rr = idx >> 5;             // 64 = r8(16) x cmb(4)
            int r8 = rr & 15, cmb = rr >> 4;
            int col = cmb * 32 + dl;       // feature col within 128-tile
            int gncol = n0 + col;
            int rem = gncol - 1536;
            int head = rem / 96, d = rem - head * 96;
            int dn = d >> 5;               // d&31 == dl
            int keybase = m0 + r8 * 8;     // 8 consecutive keys
            int b = keybase >> 12, nn = keybase & 4095;
            int kg = nn >> 5, f = (nn >> 4) & 1, hv = (nn >> 3) & 1;
            int bh = b * 8 + head;
            long chunk = (long)(bh * 128 + kg) * 6 + dn * 2 + f;
            ushort8 v8 = *reinterpret_cast<const ushort8*>(&T[col * 136 + r8 * 8]);
            *reinterpret_cast<ushort8*>(&Vf[(chunk << 9) + ((hv * 32 + dl) << 3)]) = v8;
        }
    }
}

// ---------------- Flash attention: R8 version (known-good), barrier-free L2-direct ----------------
// 256 thr = 4 waves: wr (64 q-rows), wk (kv half: 64 iters of 32 keys). Coalesced global
// b128 operand loads from frag chunks; no LDS/barriers in loop. Grid 512 = 2 blocks/CU;
// register-bound at 2 waves/SIMD (unified VGPR+AGPR ~256/wave) — do NOT raise launch_bounds.
// XCD swizzle: bh = (b0&7)*2 + (kk>>5) pins each bh's K+V (1.57MB) to one XCD L2.
__global__ __launch_bounds__(256, 2) void attn_kernel(const unsigned short* __restrict__ Qf,
                                                      const unsigned short* __restrict__ Kf,
                                                      const unsigned short* __restrict__ Vf,
                                                      unsigned short* __restrict__ Og) {
    __shared__ __align__(16) float red[4608];   // 128 x 36 epilogue reduce
    const int t = threadIdx.x;
    const int w = t >> 6, l = t & 63;
    const int wr = w >> 1, wk = w & 1;
    const int l31 = l & 31, h = l >> 5;
    const int b0 = blockIdx.x;
    const int kk = b0 >> 3;
    const int bh = (b0 & 7) * 2 + (kk >> 5);
    const int q0 = (kk & 31) * 128;
    const int voff = l << 3;   // lane's ushort offset within a chunk

    // Q fragments: 12 coalesced b128 loads, loop-invariant
    bf16x8 aq[2][6];
#pragma unroll
    for (int qn = 0; qn < 2; ++qn) {
        long qb = ((long)((bh * 128 + (q0 >> 5) + wr * 2 + qn) * 6)) << 9;
#pragma unroll
        for (int kq = 0; kq < 6; ++kq)
            aq[qn][kq] = *reinterpret_cast<const bf16x8*>(&Qf[qb + (kq << 9) + voff]);
    }

    bf16x8 ones8;
#pragma unroll
    for (int i = 0; i < 8; ++i) ones8[i] = (__bf16)1.0f;

    f32x16 acc[2][3] = {};   // [qn][dn]
    f32x16 acc_l[2] = {};

    for (int it = 0; it < 64; ++it) {
        const int kt = wk * 64 + it;
        const long kbase = ((long)((bh * 128 + kt) * 6)) << 9;
        // S^T = K_perm Q^T (32x32x16)
        f32x16 s[2] = {};
#pragma unroll
        for (int kq = 0; kq < 6; ++kq) {
            bf16x8 bk = *reinterpret_cast<const bf16x8*>(&Kf[kbase + (kq << 9) + voff]);
            s[0] = mfma32(bk, aq[0][kq], s[0]);
            s[1] = mfma32(bk, aq[1][kq], s[1]);
        }
        // p = exp2(s); C-reg -> PV A-frag slot map: frag f slot j <- reg (j&3)+8*((j>>2)&1)+4*f
        union PF { unsigned int u[4]; bf16x8 v8; } p[2][2];
#pragma unroll
        for (int qn = 0; qn < 2; ++qn) {
            float e[16];
#pragma unroll
            for (int r = 0; r < 16; ++r) e[r] = __builtin_amdgcn_exp2f(s[qn][r]);
#pragma unroll
            for (int f = 0; f < 2; ++f) {
                p[qn][f].u[0] = pk2bf(e[4 * f + 0], e[4 * f + 1]);
                p[qn][f].u[1] = pk2bf(e[4 * f + 2], e[4 * f + 3]);
                p[qn][f].u[2] = pk2bf(e[8 + 4 * f + 0], e[8 + 4 * f + 1]);
                p[qn][f].u[3] = pk2bf(e[8 + 4 * f + 2], e[8 + 4 * f + 3]);
            }
        }
        // O += P V (32x32x16), V fragments straight from L2
#pragma unroll
        for (int dn = 0; dn < 3; ++dn) {
#pragma unroll
            for (int f = 0; f < 2; ++f) {
                bf16x8 vb = *reinterpret_cast<const bf16x8*>(
                    &Vf[kbase + ((dn * 2 + f) << 9) + voff]);
                acc[0][dn] = mfma32(p[0][f].v8, vb, acc[0][dn]);
                acc[1][dn] = mfma32(p[1][f].v8, vb, acc[1][dn]);
            }
        }
#pragma unroll
        for (int qn = 0; qn < 2; ++qn)
#pragma unroll
            for (int f = 0; f < 2; ++f)
                acc_l[qn] = mfma32(p[qn][f].v8, ones8, acc_l[qn]);
    }

    // ---- cross-wave reduce over wk (pairs, stride 36 floats) ----
    const int rbase = (wr * 64 + l) * 36;
#pragma unroll
    for (int ps = 0; ps < 3; ++ps) {
        __syncthreads();
        if (wk == 1) {
#pragma unroll
            for (int c = 0; c < 2; ++c) {
                int c2 = ps * 2 + c, qn = c2 / 3, dn = c2 % 3;
#pragma unroll
                for (int u = 0; u < 4; ++u) {
                    f32x4 tmp;
#pragma unroll
                    for (int j = 0; j < 4; ++j) tmp[j] = acc[qn][dn][u * 4 + j];
                    *reinterpret_cast<f32x4*>(&red[rbase + c * 16 + u * 4]) = tmp;
                }
            }
        }
        __syncthreads();
        if (wk == 0) {
#pragma unroll
            for (int c = 0; c < 2; ++c) {
                int c2 = ps * 2 + c, qn = c2 / 3, dn = c2 % 3;
#pragma unroll
                for (int u = 0; u < 4; ++u) {
                    f32x4 tmp = *reinterpret_cast<const f32x4*>(&red[rbase + c * 16 + u * 4]);
#pragma unroll
                    for (int j = 0; j < 4; ++j) acc[qn][dn][u * 4 + j] += tmp[j];
                }
            }
        }
    }
    __syncthreads();
    if (wk == 1) {
#pragma unroll
        for (int qn = 0; qn < 2; ++qn)
#pragma unroll
            for (int u = 0; u < 4; ++u) {
                f32x4 tmp;
#pragma unroll
                for (int j = 0; j < 4; ++j) tmp[j] = acc_l[qn][u * 4 + j];
                *reinterpret_cast<f32x4*>(&red[rbase + qn * 16 + u * 4]) = tmp;
            }
    }
    __syncthreads();
    if (wk == 0) {
#pragma unroll
        for (int qn = 0; qn < 2; ++qn)
#pragma unroll
            for (int u = 0; u < 4; ++u) {
                f32x4 tmp = *reinterpret_cast<const f32x4*>(&red[rbase + qn * 16 + u * 4]);
#pragma unroll
                for (int j = 0; j < 4; ++j) acc_l[qn][u * 4 + j] += tmp[j];
            }
        // normalize + write attn_out[b][n][head*96+d] (bf16 scratch)
        const int b = bh >> 3, head = bh & 7;
#pragma unroll
        for (int qn = 0; qn < 2; ++qn) {
#pragma unroll
            for (int reg = 0; reg < 16; ++reg) {
                int qloc = (reg & 3) + 8 * (reg >> 2) + 4 * h;
                int n = q0 + wr * 64 + qn * 32 + qloc;
                float inv = 1.f / acc_l[qn][reg];
                int rowoff = (b * 4096 + n) * 768 + head * 96;
#pragma unroll
                for (int dn = 0; dn < 3; ++dn)
                    Og[rowoff + dn * 32 + l31] = f2bf(acc[qn][dn][reg] * inv);
            }
        }
    }
}

// ---------------- proj GEMM: [8192x768] x [768x768]^T -> FP32 out ----------------
__global__ __launch_bounds__(256) void proj_gemm(const unsigned short* __restrict__ A,
                                                 const unsigned short* __restrict__ W,
                                                 float* __restrict__ out) {
    __shared__ __align__(16) unsigned short As[128 * 40];
    __shared__ __align__(16) unsigned short Bs[128 * 40];
    const int t = threadIdx.x;
    const int w = t >> 6, l = t & 63;
    const int wm = (w >> 1) * 64, wn = (w & 1) * 64;
    const int lr = l & 15, lq = l >> 4;
    const int m0 = blockIdx.y * 128, n0 = blockIdx.x * 128;
    f32x4 acc[4][4] = {};
    for (int k0 = 0; k0 < 768; k0 += 32) {
        __syncthreads();
#pragma unroll
        for (int i = 0; i < 2; ++i) {
            int v = t + i * 256;
            int r = v >> 2, c8 = (v & 3) * 8;
            *reinterpret_cast<ushort8*>(&As[r * 40 + c8]) =
                *reinterpret_cast<const ushort8*>(&A[(m0 + r) * 768 + k0 + c8]);
            *reinterpret_cast<ushort8*>(&Bs[r * 40 + c8]) =
                *reinterpret_cast<const ushort8*>(&W[(n0 + r) * 768 + k0 + c8]);
        }
        __syncthreads();
        bf16x8 af[4], bfr[4];
#pragma unroll
        for (int mt = 0; mt < 4; ++mt)
            af[mt] = *reinterpret_cast<const bf16x8*>(&As[(wm + mt * 16 + lr) * 40 + lq * 8]);
#pragma unroll
        for (int nt = 0; nt < 4; ++nt)
            bfr[nt] = *reinterpret_cast<const bf16x8*>(&Bs[(wn + nt * 16 + lr) * 40 + lq * 8]);
#pragma unroll
        for (int mt = 0; mt < 4; ++mt)
#pragma unroll
            for (int nt = 0; nt < 4; ++nt)
                acc[mt][nt] = mfma16(af[mt], bfr[nt], acc[mt][nt]);
    }
#pragma unroll
    for (int nt = 0; nt < 4; ++nt) {
        int gn = n0 + wn + nt * 16 + lr;
#pragma unroll
        for (int mt = 0; mt < 4; ++mt) {
#pragma unroll
            for (int r = 0; r < 4; ++r) {
                int gm = m0 + wm + mt * 16 + lq * 4 + r;
                out[gm * 768 + gn] = acc[mt][nt][r];
            }
        }
    }
}

extern "C" void kernel_launch(void* const* d_in, const int* in_sizes, int n_in,
                              void* d_out, int out_size, void* d_ws, size_t ws_size,
                              hipStream_t stream) {
    const float* x     = (const float*)d_in[0];   // [2,4096,768] fp32
    const float* wqkv  = (const float*)d_in[1];   // [2304,768] fp32
    const float* wproj = (const float*)d_in[2];   // [768,768] fp32
    float* out = (float*)d_out;                   // fp32 [2,4096,768]
    char* ws = (char*)d_ws;
    unsigned short* xb     = (unsigned short*)(ws);             // 12582912
    unsigned short* wqkvb  = (unsigned short*)(ws + 12582912);  // 3538944
    unsigned short* wprojb = (unsigned short*)(ws + 16121856);  // 1179648
    unsigned short* Qf     = (unsigned short*)(ws + 17301504);  // frag chunks
    unsigned short* Kf     = (unsigned short*)(ws + 29884416);  // frag chunks
    unsigned short* Vf     = (unsigned short*)(ws + 42467328);  // frag chunks
    unsigned short* attnb  = xb;                                // reuse: [B,N,C] bf16

    cvt3_f32_bf16<<<8448, 256, 0, stream>>>(x, wqkv, wproj, xb, wqkvb, wprojb);
    qkv_gemm<<<dim3(18, 64), 256, 0, stream>>>(xb, wqkvb, Qf, Kf, Vf);
    attn_kernel<<<512, 256, 0, stream>>>(Qf, Kf, Vf, attnb);
    proj_gemm<<<dim3(6, 64), 256, 0, stream>>>(attnb, wprojb, out);
}

// Round 11
// 282.042 us; speedup vs baseline: 3.9682x; 1.0066x over previous
//
#include <hip/hip_runtime.h>

typedef __bf16 bf16;
typedef __attribute__((ext_vector_type(8))) __bf16 bf16x8;
typedef __attribute__((ext_vector_type(2))) __bf16 bf16x2;
typedef __attribute__((ext_vector_type(4))) float f32x4;
typedef __attribute__((ext_vector_type(16))) float f32x16;
typedef __attribute__((ext_vector_type(8))) unsigned short ushort8;   // 16B
typedef __attribute__((ext_vector_type(4))) unsigned short ushort4v;  // 8B

__device__ __forceinline__ unsigned short f2bf(float f) {
    union { float f; unsigned int u; } v; v.f = f;
    unsigned int u = v.u;
    return (unsigned short)((u + 0x7fffu + ((u >> 16) & 1u)) >> 16);
}

#if __has_builtin(__builtin_amdgcn_cvt_pk_bf16_f32)
__device__ __forceinline__ unsigned int pk2bf(float a, float b) {
    union { bf16x2 v; unsigned int u; } c;
    c.v = __builtin_amdgcn_cvt_pk_bf16_f32(a, b);
    return c.u;
}
#else
__device__ __forceinline__ unsigned int pk2bf(float a, float b) {
    return (unsigned int)f2bf(a) | ((unsigned int)f2bf(b) << 16);
}
#endif

__device__ __forceinline__ f32x4 mfma16(bf16x8 a, bf16x8 b, f32x4 c) {
    return __builtin_amdgcn_mfma_f32_16x16x32_bf16(a, b, c, 0, 0, 0);
}
__device__ __forceinline__ f32x16 mfma32(bf16x8 a, bf16x8 b, f32x16 c) {
    return __builtin_amdgcn_mfma_f32_32x32x16_bf16(a, b, c, 0, 0, 0);
}

// async global->LDS 16B: HW places lane i's data at ldsbase + i*16 (wave-uniform base).
#if __has_builtin(__builtin_amdgcn_global_load_lds)
__device__ __forceinline__ void gload16(const unsigned short* g, unsigned short* l) {
    typedef const unsigned int __attribute__((address_space(1)))* gp_t;
    typedef unsigned int __attribute__((address_space(3)))* lp_t;
    __builtin_amdgcn_global_load_lds((gp_t)(const void*)g, (lp_t)(void*)l, 16, 0, 0);
}
#define GLL_LANE 1
#else
#define GLL_LANE 0
#endif

// ---------------- fused fp32 -> bf16 convert ----------------
__global__ void cvt3_f32_bf16(const float* __restrict__ x, const float* __restrict__ wq,
                              const float* __restrict__ wp,
                              unsigned short* __restrict__ xb, unsigned short* __restrict__ wqb,
                              unsigned short* __restrict__ wpb) {
    int i = blockIdx.x * 256 + threadIdx.x;   // float4 index
    const float* in; unsigned short* out; int base;
    if (i < 1572864)      { in = x;  out = xb;  base = i; }
    else if (i < 2015232) { in = wq; out = wqb; base = i - 1572864; }
    else if (i < 2162688) { in = wp; out = wpb; base = i - 2015232; }
    else return;
    float4 f = reinterpret_cast<const float4*>(in)[base];
    union { ushort4v v; unsigned int u[2]; } o;
    o.u[0] = pk2bf(f.x, f.y);
    o.u[1] = pk2bf(f.z, f.w);
    reinterpret_cast<ushort4v*>(out)[base] = o.v;
}

// key permutation for 32x32 S^T C-layout -> PV A-layout:  p: a -> bits (a0,a1,a3,a4,a2)
__device__ __forceinline__ int kperm(int k5) {
    return (k5 & 3) | (((k5 >> 3) & 1) << 2) | (((k5 >> 4) & 1) << 3) | (((k5 >> 2) & 1) << 4);
}
__device__ __forceinline__ int kperm_inv(int p5) {
    return (p5 & 3) | (((p5 >> 4) & 1) << 2) | (((p5 >> 2) & 1) << 3) | (((p5 >> 3) & 1) << 4);
}

// ---------------- QKV GEMM -> fragment-ready chunked layouts ----------------
// K-loop staging now via global_load_lds width=16 (m97 pattern): LDS unpadded stride 32,
// byte dest = v*16 = wave_base + lane*16. MFMA body / coalesced epilogue unchanged from R9.
__global__ __launch_bounds__(256) void qkv_gemm(const unsigned short* __restrict__ A,
                                                const unsigned short* __restrict__ W,
                                                unsigned short* __restrict__ Qf,
                                                unsigned short* __restrict__ Kf,
                                                unsigned short* __restrict__ Vf) {
    __shared__ __align__(16) char smem[34816];
    unsigned short* As = (unsigned short*)smem;            // 128x32 (8 KB)
    unsigned short* Bs = (unsigned short*)(smem + 8192);   // 128x32 (8 KB)
    unsigned short* T  = (unsigned short*)smem;            // epilogue tile 128x136 (34816 B)
    const int t = threadIdx.x;
    const int w = t >> 6, l = t & 63;
    const int wm = (w >> 1) * 64, wn = (w & 1) * 64;
    const int lr = l & 15, lq = l >> 4;
    const int m0 = blockIdx.y * 128, n0 = blockIdx.x * 128;
    f32x4 acc[4][4] = {};
    for (int k0 = 0; k0 < 768; k0 += 32) {
        __syncthreads();
#pragma unroll
        for (int i = 0; i < 2; ++i) {
            int v = t + i * 256;
            int r = v >> 2, c8 = (v & 3) * 8;
#if GLL_LANE
            gload16(&A[(m0 + r) * 768 + k0 + c8], &As[(w * 64 + i * 256) * 8]);
            gload16(&W[(n0 + r) * 768 + k0 + c8], &Bs[(w * 64 + i * 256) * 8]);
#else
            *reinterpret_cast<ushort8*>(&As[r * 32 + c8]) =
                *reinterpret_cast<const ushort8*>(&A[(m0 + r) * 768 + k0 + c8]);
            *reinterpret_cast<ushort8*>(&Bs[r * 32 + c8]) =
                *reinterpret_cast<const ushort8*>(&W[(n0 + r) * 768 + k0 + c8]);
#endif
        }
        __syncthreads();   // compiler drains vmcnt(0) before s_barrier -> LDS data visible
        bf16x8 af[4], bfr[4];
#pragma unroll
        for (int mt = 0; mt < 4; ++mt)
            af[mt] = *reinterpret_cast<const bf16x8*>(&As[(wm + mt * 16 + lr) * 32 + lq * 8]);
#pragma unroll
        for (int nt = 0; nt < 4; ++nt)
            bfr[nt] = *reinterpret_cast<const bf16x8*>(&Bs[(wn + nt * 16 + lr) * 32 + lq * 8]);
#pragma unroll
        for (int mt = 0; mt < 4; ++mt)
#pragma unroll
            for (int nt = 0; nt < 4; ++nt)
                acc[mt][nt] = mfma16(af[mt], bfr[nt], acc[mt][nt]);
    }
    // ---- epilogue: C tile -> LDS (V region transposed) -> coalesced b128 stores ----
    const int tsel = n0 / 768;   // whole block is one of Q/K/V
    __syncthreads();             // As/Bs fragment reads done; reuse as T
    if (tsel < 2) {
#pragma unroll
        for (int nt = 0; nt < 4; ++nt)
#pragma unroll
            for (int mt = 0; mt < 4; ++mt)
#pragma unroll
                for (int r = 0; r < 4; ++r) {
                    int row = wm + mt * 16 + lq * 4 + r;
                    int col = wn + nt * 16 + lr;
                    float val = acc[mt][nt][r];
                    if (tsel == 0) val *= 0.14724444f;   // SCALE*log2e
                    T[row * 136 + col] = f2bf(val);
                }
    } else {
#pragma unroll
        for (int nt = 0; nt < 4; ++nt)
#pragma unroll
            for (int mt = 0; mt < 4; ++mt)
#pragma unroll
                for (int r = 0; r < 4; ++r) {
                    int row = wm + mt * 16 + lq * 4 + r;   // key token
                    int col = wn + nt * 16 + lr;           // feature
                    T[col * 136 + row] = f2bf(acc[mt][nt][r]);  // transposed
                }
    }
    __syncthreads();
    if (tsel < 2) {
#pragma unroll
        for (int i = 0; i < 8; ++i) {
            int idx = t + i * 256;
            int pos31 = idx & 31;          // store position within 32-group
            int rest = idx >> 5;           // 64 = c8(16) x qg(4)
            int c8 = rest & 15, qg = rest >> 4;
            int l31 = (tsel == 1) ? kperm_inv(pos31) : pos31;  // token row in tile
            int gncol = n0 + c8 * 8;
            int rem = gncol - tsel * 768;
            int head = rem / 96, d = rem - head * 96;
            int kq = d >> 4, h2 = (d >> 3) & 1;
            int gm = m0 + qg * 32 + l31;
            int b = gm >> 12, nn = gm & 4095;
            int bh = b * 8 + head;
            long chunk = (long)(bh * 128 + (nn >> 5)) * 6 + kq;
            ushort8 v8 = *reinterpret_cast<const ushort8*>(&T[(qg * 32 + l31) * 136 + c8 * 8]);
            unsigned short* dst = (tsel == 0) ? Qf : Kf;
            *reinterpret_cast<ushort8*>(&dst[(chunk << 9) + ((h2 * 32 + pos31) << 3)]) = v8;
        }
    } else {
#pragma unroll
        for (int i = 0; i < 8; ++i) {
            int idx = t + i * 256;
            int dl = idx & 31;
            int rr = idx >> 5;             // 64 = r8(16) x cmb(4)
            int r8 = rr & 15, cmb = rr >> 4;
            int col = cmb * 32 + dl;       // feature col within 128-tile
            int gncol = n0 + col;
            int rem = gncol - 1536;
            int head = rem / 96, d = rem - head * 96;
            int dn = d >> 5;               // d&31 == dl
            int keybase = m0 + r8 * 8;     // 8 consecutive keys
            int b = keybase >> 12, nn = keybase & 4095;
            int kg = nn >> 5, f = (nn >> 4) & 1, hv = (nn >> 3) & 1;
            int bh = b * 8 + head;
            long chunk = (long)(bh * 128 + kg) * 6 + dn * 2 + f;
            ushort8 v8 = *reinterpret_cast<const ushort8*>(&T[col * 136 + r8 * 8]);
            *reinterpret_cast<ushort8*>(&Vf[(chunk << 9) + ((hv * 32 + dl) << 3)]) = v8;
        }
    }
}

// ---------------- Flash attention: R8/R10 version (known-good) — UNTOUCHED ----------------
__global__ __launch_bounds__(256, 2) void attn_kernel(const unsigned short* __restrict__ Qf,
                                                      const unsigned short* __restrict__ Kf,
                                                      const unsigned short* __restrict__ Vf,
                                                      unsigned short* __restrict__ Og) {
    __shared__ __align__(16) float red[4608];   // 128 x 36 epilogue reduce
    const int t = threadIdx.x;
    const int w = t >> 6, l = t & 63;
    const int wr = w >> 1, wk = w & 1;
    const int l31 = l & 31, h = l >> 5;
    const int b0 = blockIdx.x;
    const int kk = b0 >> 3;
    const int bh = (b0 & 7) * 2 + (kk >> 5);
    const int q0 = (kk & 31) * 128;
    const int voff = l << 3;   // lane's ushort offset within a chunk

    bf16x8 aq[2][6];
#pragma unroll
    for (int qn = 0; qn < 2; ++qn) {
        long qb = ((long)((bh * 128 + (q0 >> 5) + wr * 2 + qn) * 6)) << 9;
#pragma unroll
        for (int kq = 0; kq < 6; ++kq)
            aq[qn][kq] = *reinterpret_cast<const bf16x8*>(&Qf[qb + (kq << 9) + voff]);
    }

    bf16x8 ones8;
#pragma unroll
    for (int i = 0; i < 8; ++i) ones8[i] = (__bf16)1.0f;

    f32x16 acc[2][3] = {};   // [qn][dn]
    f32x16 acc_l[2] = {};

    for (int it = 0; it < 64; ++it) {
        const int kt = wk * 64 + it;
        const long kbase = ((long)((bh * 128 + kt) * 6)) << 9;
        f32x16 s[2] = {};
#pragma unroll
        for (int kq = 0; kq < 6; ++kq) {
            bf16x8 bk = *reinterpret_cast<const bf16x8*>(&Kf[kbase + (kq << 9) + voff]);
            s[0] = mfma32(bk, aq[0][kq], s[0]);
            s[1] = mfma32(bk, aq[1][kq], s[1]);
        }
        union PF { unsigned int u[4]; bf16x8 v8; } p[2][2];
#pragma unroll
        for (int qn = 0; qn < 2; ++qn) {
            float e[16];
#pragma unroll
            for (int r = 0; r < 16; ++r) e[r] = __builtin_amdgcn_exp2f(s[qn][r]);
#pragma unroll
            for (int f = 0; f < 2; ++f) {
                p[qn][f].u[0] = pk2bf(e[4 * f + 0], e[4 * f + 1]);
                p[qn][f].u[1] = pk2bf(e[4 * f + 2], e[4 * f + 3]);
                p[qn][f].u[2] = pk2bf(e[8 + 4 * f + 0], e[8 + 4 * f + 1]);
                p[qn][f].u[3] = pk2bf(e[8 + 4 * f + 2], e[8 + 4 * f + 3]);
            }
        }
#pragma unroll
        for (int dn = 0; dn < 3; ++dn) {
#pragma unroll
            for (int f = 0; f < 2; ++f) {
                bf16x8 vb = *reinterpret_cast<const bf16x8*>(
                    &Vf[kbase + ((dn * 2 + f) << 9) + voff]);
                acc[0][dn] = mfma32(p[0][f].v8, vb, acc[0][dn]);
                acc[1][dn] = mfma32(p[1][f].v8, vb, acc[1][dn]);
            }
        }
#pragma unroll
        for (int qn = 0; qn < 2; ++qn)
#pragma unroll
            for (int f = 0; f < 2; ++f)
                acc_l[qn] = mfma32(p[qn][f].v8, ones8, acc_l[qn]);
    }

    // ---- cross-wave reduce over wk (pairs, stride 36 floats) ----
    const int rbase = (wr * 64 + l) * 36;
#pragma unroll
    for (int ps = 0; ps < 3; ++ps) {
        __syncthreads();
        if (wk == 1) {
#pragma unroll
            for (int c = 0; c < 2; ++c) {
                int c2 = ps * 2 + c, qn = c2 / 3, dn = c2 % 3;
#pragma unroll
                for (int u = 0; u < 4; ++u) {
                    f32x4 tmp;
#pragma unroll
                    for (int j = 0; j < 4; ++j) tmp[j] = acc[qn][dn][u * 4 + j];
                    *reinterpret_cast<f32x4*>(&red[rbase + c * 16 + u * 4]) = tmp;
                }
            }
        }
        __syncthreads();
        if (wk == 0) {
#pragma unroll
            for (int c = 0; c < 2; ++c) {
                int c2 = ps * 2 + c, qn = c2 / 3, dn = c2 % 3;
#pragma unroll
                for (int u = 0; u < 4; ++u) {
                    f32x4 tmp = *reinterpret_cast<const f32x4*>(&red[rbase + c * 16 + u * 4]);
#pragma unroll
                    for (int j = 0; j < 4; ++j) acc[qn][dn][u * 4 + j] += tmp[j];
                }
            }
        }
    }
    __syncthreads();
    if (wk == 1) {
#pragma unroll
        for (int qn = 0; qn < 2; ++qn)
#pragma unroll
            for (int u = 0; u < 4; ++u) {
                f32x4 tmp;
#pragma unroll
                for (int j = 0; j < 4; ++j) tmp[j] = acc_l[qn][u * 4 + j];
                *reinterpret_cast<f32x4*>(&red[rbase + qn * 16 + u * 4]) = tmp;
            }
    }
    __syncthreads();
    if (wk == 0) {
#pragma unroll
        for (int qn = 0; qn < 2; ++qn)
#pragma unroll
            for (int u = 0; u < 4; ++u) {
                f32x4 tmp = *reinterpret_cast<const f32x4*>(&red[rbase + qn * 16 + u * 4]);
#pragma unroll
                for (int j = 0; j < 4; ++j) acc_l[qn][u * 4 + j] += tmp[j];
            }
        const int b = bh >> 3, head = bh & 7;
#pragma unroll
        for (int qn = 0; qn < 2; ++qn) {
#pragma unroll
            for (int reg = 0; reg < 16; ++reg) {
                int qloc = (reg & 3) + 8 * (reg >> 2) + 4 * h;
                int n = q0 + wr * 64 + qn * 32 + qloc;
                float inv = 1.f / acc_l[qn][reg];
                int rowoff = (b * 4096 + n) * 768 + head * 96;
#pragma unroll
                for (int dn = 0; dn < 3; ++dn)
                    Og[rowoff + dn * 32 + l31] = f2bf(acc[qn][dn][reg] * inv);
            }
        }
    }
}

// ---------------- proj GEMM: [8192x768] x [768x768]^T -> FP32 out ----------------
// Staging via global_load_lds (same pattern as qkv).
__global__ __launch_bounds__(256) void proj_gemm(const unsigned short* __restrict__ A,
                                                 const unsigned short* __restrict__ W,
                                                 float* __restrict__ out) {
    __shared__ __align__(16) unsigned short As[128 * 32];
    __shared__ __align__(16) unsigned short Bs[128 * 32];
    const int t = threadIdx.x;
    const int w = t >> 6, l = t & 63;
    const int wm = (w >> 1) * 64, wn = (w & 1) * 64;
    const int lr = l & 15, lq = l >> 4;
    const int m0 = blockIdx.y * 128, n0 = blockIdx.x * 128;
    f32x4 acc[4][4] = {};
    for (int k0 = 0; k0 < 768; k0 += 32) {
        __syncthreads();
#pragma unroll
        for (int i = 0; i < 2; ++i) {
            int v = t + i * 256;
            int r = v >> 2, c8 = (v & 3) * 8;
#if GLL_LANE
            gload16(&A[(m0 + r) * 768 + k0 + c8], &As[(w * 64 + i * 256) * 8]);
            gload16(&W[(n0 + r) * 768 + k0 + c8], &Bs[(w * 64 + i * 256) * 8]);
#else
            *reinterpret_cast<ushort8*>(&As[r * 32 + c8]) =
                *reinterpret_cast<const ushort8*>(&A[(m0 + r) * 768 + k0 + c8]);
            *reinterpret_cast<ushort8*>(&Bs[r * 32 + c8]) =
                *reinterpret_cast<const ushort8*>(&W[(n0 + r) * 768 + k0 + c8]);
#endif
        }
        __syncthreads();
        bf16x8 af[4], bfr[4];
#pragma unroll
        for (int mt = 0; mt < 4; ++mt)
            af[mt] = *reinterpret_cast<const bf16x8*>(&As[(wm + mt * 16 + lr) * 32 + lq * 8]);
#pragma unroll
        for (int nt = 0; nt < 4; ++nt)
            bfr[nt] = *reinterpret_cast<const bf16x8*>(&Bs[(wn + nt * 16 + lr) * 32 + lq * 8]);
#pragma unroll
        for (int mt = 0; mt < 4; ++mt)
#pragma unroll
            for (int nt = 0; nt < 4; ++nt)
                acc[mt][nt] = mfma16(af[mt], bfr[nt], acc[mt][nt]);
    }
#pragma unroll
    for (int nt = 0; nt < 4; ++nt) {
        int gn = n0 + wn + nt * 16 + lr;
#pragma unroll
        for (int mt = 0; mt < 4; ++mt) {
#pragma unroll
            for (int r = 0; r < 4; ++r) {
                int gm = m0 + wm + mt * 16 + lq * 4 + r;
                out[gm * 768 + gn] = acc[mt][nt][r];
            }
        }
    }
}

extern "C" void kernel_launch(void* const* d_in, const int* in_sizes, int n_in,
                              void* d_out, int out_size, void* d_ws, size_t ws_size,
                              hipStream_t stream) {
    const float* x     = (const float*)d_in[0];   // [2,4096,768] fp32
    const float* wqkv  = (const float*)d_in[1];   // [2304,768] fp32
    const float* wproj = (const float*)d_in[2];   // [768,768] fp32
    float* out = (float*)d_out;                   // fp32 [2,4096,768]
    char* ws = (char*)d_ws;
    unsigned short* xb     = (unsigned short*)(ws);             // 12582912
    unsigned short* wqkvb  = (unsigned short*)(ws + 12582912);  // 3538944
    unsigned short* wprojb = (unsigned short*)(ws + 16121856);  // 1179648
    unsigned short* Qf     = (unsigned short*)(ws + 17301504);  // frag chunks
    unsigned short* Kf     = (unsigned short*)(ws + 29884416);  // frag chunks
    unsigned short* Vf     = (unsigned short*)(ws + 42467328);  // frag chunks
    unsigned short* attnb  = xb;                                // reuse: [B,N,C] bf16

    cvt3_f32_bf16<<<8448, 256, 0, stream>>>(x, wqkv, wproj, xb, wqkvb, wprojb);
    qkv_gemm<<<dim3(18, 64), 256, 0, stream>>>(xb, wqkvb, Qf, Kf, Vf);
    attn_kernel<<<512, 256, 0, stream>>>(Qf, Kf, Vf, attnb);
    proj_gemm<<<dim3(6, 64), 256, 0, stream>>>(attnb, wprojb, out);
}